// Round 3
// baseline (749.149 us; speedup 1.0000x reference)
//
#include <hip/hip_runtime.h>

// DeepSeek-V2 expert MLP, fp8-block-dequant weights. T=8192, H=5120, F=1536.
// Pipeline (3 dispatches):
//   1) prep: x f32->bf16; wg,wu dequant->bf16 INTERLEAVED into wq[3072][5120];
//      wd dequant->bf16 wdq[5120][1536].  (unchanged, verified)
//   2) gemm_p<FUSE_SILU>: h = silu/up-pair epilogue of xb @ wq^T.
//   3) gemm_p<plain>: out = h @ wdq^T, f32.
// GEMM round-3: m201-template geometry. BM=BN=256, 512 thr = 8 waves
// (2M x 4N, per-wave 128x64, acc[8][4]). kslice (BK=32) ring-4:
// 4 x {A 16KB | B 16KB} = 128 KB LDS, 1 block/CU. Per kslice: 2 phases x
// {ds_read | stage-issue | bar | lgkmcnt(0) | setprio 16 MFMA | bar},
// counted s_waitcnt vmcnt(8) once per kslice (4 loads/kslice x 3 in flight
// = 12 outstanding -> wait to 8 drains exactly the next kslice) [T3/T4].
// Main loop unrolled x4 -> ring indices compile-time. Kept verified: XOR
// swizzle (0 conflicts), linear glds dest + inverse-swizzled global src
// (rule #21), setprio [T5], bijective XCD chunk swizzle [T1].

typedef __bf16 bf16x8 __attribute__((ext_vector_type(8)));
typedef float  f32x4  __attribute__((ext_vector_type(4)));

__device__ __forceinline__ void glds16(const __bf16* g, __bf16* l) {
  __builtin_amdgcn_global_load_lds(
      (const __attribute__((address_space(1))) void*)g,
      (__attribute__((address_space(3))) void*)l, 16, 0, 0);
}

// Inverse of the read-side swizzle: for linear 16B LDS chunk c of a 16 KB
// region, which logical (row, k) must be fetched there. Subtile = 16 rows x
// 32 bf16 = 1024 B; storage byte = logical ^ ((row&8)<<2) ^ ((row&2)<<3).
__device__ __forceinline__ void chunk_rk(int c, int& row, int& k) {
  int s = c >> 6;                 // subtile index (16 rows each)
  int w = (c & 63) << 4;          // storage byte within subtile
  int wl = w ^ (((w >> 9) & 1) << 5) ^ (((w >> 7) & 1) << 4);
  row = (s << 4) + (wl >> 6);
  k = (wl & 63) >> 1;
}

#define BAR()                               \
  do {                                      \
    __builtin_amdgcn_sched_barrier(0);      \
    asm volatile("s_barrier" ::: "memory"); \
    __builtin_amdgcn_sched_barrier(0);      \
  } while (0)

#define LGKM0()                                        \
  do {                                                 \
    asm volatile("s_waitcnt lgkmcnt(0)" ::: "memory"); \
    __builtin_amdgcn_sched_barrier(0);                 \
  } while (0)

#define VMBAR(n)                                                       \
  do {                                                                 \
    __builtin_amdgcn_sched_barrier(0);                                 \
    asm volatile("s_waitcnt vmcnt(" #n ")\n\ts_barrier" ::: "memory"); \
    __builtin_amdgcn_sched_barrier(0);                                 \
  } while (0)

// ---- fused prep: xcast + 3 dequants in one launch (unchanged) -------------
__device__ __forceinline__ void cast8(const float* __restrict__ in,
                                      __bf16* __restrict__ out, size_t idx) {
  f32x4 a = *(const f32x4*)(in + idx);
  f32x4 b = *(const f32x4*)(in + idx + 4);
  bf16x8 o;
#pragma unroll
  for (int i = 0; i < 4; ++i) { o[i] = (__bf16)a[i]; o[i + 4] = (__bf16)b[i]; }
  *(bf16x8*)(out + idx) = o;
}

__device__ __forceinline__ void dq_ilv(const float* __restrict__ w,
                                       const float* __restrict__ s,
                                       __bf16* __restrict__ wq, int r, int tid,
                                       int which) {
  unsigned idx = ((unsigned)r * 256u + (unsigned)tid) * 8u;
  unsigned f = idx / 5120u;
  unsigned h = idx - f * 5120u;
  float sc = s[(f >> 7) * 40 + (h >> 7)];
  f32x4 a = *(const f32x4*)(w + idx);
  f32x4 b = *(const f32x4*)(w + idx + 4);
  bf16x8 o;
#pragma unroll
  for (int i = 0; i < 4; ++i) {
    o[i] = (__bf16)(a[i] * sc);
    o[i + 4] = (__bf16)(b[i] * sc);
  }
  *(bf16x8*)(wq + (size_t)(2 * f + which) * 5120 + h) = o;
}

__device__ __forceinline__ void dq_wd(const float* __restrict__ w,
                                      const float* __restrict__ s,
                                      __bf16* __restrict__ o8, int r, int tid) {
  unsigned idx = ((unsigned)r * 256u + (unsigned)tid) * 8u;
  unsigned f = idx / 1536u;
  unsigned h = idx - f * 1536u;
  float sc = s[(f >> 7) * 12 + (h >> 7)];
  f32x4 a = *(const f32x4*)(w + idx);
  f32x4 b = *(const f32x4*)(w + idx + 4);
  bf16x8 o;
#pragma unroll
  for (int i = 0; i < 4; ++i) {
    o[i] = (__bf16)(a[i] * sc);
    o[i + 4] = (__bf16)(b[i] * sc);
  }
  *(bf16x8*)(o8 + idx) = o;
}

__global__ void prep(const float* __restrict__ x, const float* __restrict__ wg,
                     const float* __restrict__ sg, const float* __restrict__ wu,
                     const float* __restrict__ su, const float* __restrict__ wd,
                     const float* __restrict__ sd, __bf16* __restrict__ xb,
                     __bf16* __restrict__ wq, __bf16* __restrict__ wdq) {
  int bid = blockIdx.x;
  int tid = threadIdx.x;
  if (bid < 20480) {
    cast8(x, xb, ((size_t)bid * 256 + tid) * 8);
  } else if (bid < 24320) {
    dq_ilv(wg, sg, wq, bid - 20480, tid, 0);
  } else if (bid < 28160) {
    dq_ilv(wu, su, wq, bid - 24320, tid, 1);
  } else {
    dq_wd(wd, sd, wdq, bid - 28160, tid);
  }
}

// ---- m201-geometry GEMM: C = A @ B^T --------------------------------------
// A:[M,K] bf16, B:[N,K] bf16. Tile 256x256, kslice ring-4, 128 KB LDS.

#define STAGE_A(t_, es_)                     \
  do {                                       \
    __bf16* lp = lds + (es_) * 16384;        \
    const unsigned ko = (unsigned)(t_) << 5; \
    glds16(Ab + (off0 + ko), lp + d0);       \
    glds16(Ab + (off1 + ko), lp + d1);       \
  } while (0)

#define STAGE_B(t_, es_)                     \
  do {                                       \
    __bf16* lp = lds + (es_) * 16384 + 8192; \
    const unsigned ko = (unsigned)(t_) << 5; \
    glds16(Bb + (off0 + ko), lp + d0);       \
    glds16(Bb + (off1 + ko), lp + d1);       \
  } while (0)

#define RD_AF(e_, h_)                                                       \
  do {                                                                      \
    const char* b_ = (const char*)lds + (e_) * 32768;                       \
    _Pragma("unroll") for (int i = 0; i < 4; ++i) af[i] =                   \
        *(const bf16x8*)(b_ + ((a_sub + (h_) * 4 + i) << 10) + laneoff);    \
  } while (0)

#define RD_BG(e_)                                                 \
  do {                                                            \
    const char* b_ = (const char*)lds + (e_) * 32768 + 16384;     \
    _Pragma("unroll") for (int j = 0; j < 4; ++j) bg[j] =         \
        *(const bf16x8*)(b_ + ((b_sub + j) << 10) + laneoff);     \
  } while (0)

#define MFMA16(h_)                                                          \
  do {                                                                      \
    __builtin_amdgcn_s_setprio(1);                                          \
    _Pragma("unroll") for (int j = 0; j < 4; ++j)                           \
        _Pragma("unroll") for (int i = 0; i < 4; ++i) acc[(h_) * 4 + i][j] = \
            __builtin_amdgcn_mfma_f32_16x16x32_bf16(                        \
                af[i], bg[j], acc[(h_) * 4 + i][j], 0, 0, 0);               \
    __builtin_amdgcn_s_setprio(0);                                          \
  } while (0)

// one kslice step: 2 phases x {reads | stage-issue | bar | lgkm0 | 16 MFMA}
#define KSTEP(e_, SA, SB, TRAIL) \
  do {                           \
    RD_AF(e_, 0);                \
    RD_BG(e_);                   \
    SA;                          \
    BAR();                       \
    LGKM0();                     \
    MFMA16(0);                   \
    BAR();                       \
    RD_AF(e_, 1);                \
    SB;                          \
    BAR();                       \
    LGKM0();                     \
    MFMA16(1);                   \
    TRAIL;                       \
  } while (0)

template <bool FUSE_SILU, typename OutT>
__global__ __launch_bounds__(512, 2) void gemm_p(
    const __bf16* __restrict__ A, const __bf16* __restrict__ B,
    OutT* __restrict__ C, int M, int N, int K, int ldc, int nbx) {
  __shared__ __bf16 lds[4 * 16384];  // 4 ring slots x {A 16KB | B 16KB}
  const int tid = threadIdx.x;
  const int lane = tid & 63;
  const int wave = tid >> 6;
  const int lr = lane & 15;

  // bijective XCD-chunked swizzle (gridDim.x % 8 == 0 by construction)
  const int nwg = gridDim.x;
  const int lb = (blockIdx.x & 7) * (nwg >> 3) + (blockIdx.x >> 3);
  const int bx = lb % nbx;
  const int by = lb / nbx;
  const int m0 = by * 256, n0 = bx * 256;

  // per-lane fragment byte offset within a 1 KB subtile, swizzled
  int laneoff = (lr << 6) | ((lane >> 4) << 4);
  laneoff ^= ((lr & 2) << 3) | ((lr & 8) << 2);
  const int wrow = wave >> 2;        // 2 M-waves
  const int wcol = wave & 3;         // 4 N-waves
  const int a_sub = wrow << 3;       // A subtile base (8 frags of 16 rows)
  const int b_sub = wcol << 2;       // B subtile base (4 frags)

  // staging: per kslice each thread loads 2 A-chunks + 2 B-chunks (16B each);
  // inverse-swizzled global source, linear LDS destination.
  int r0, k0, r1, k1;
  chunk_rk(tid, r0, k0);
  chunk_rk(tid + 512, r1, k1);
  const __bf16* Ab = A + (size_t)m0 * K;
  const __bf16* Bb = B + (size_t)n0 * K;
  const unsigned off0 = (unsigned)r0 * K + (unsigned)k0;
  const unsigned off1 = (unsigned)r1 * K + (unsigned)k1;
  const int d0 = tid << 3, d1 = (tid + 512) << 3;

  f32x4 acc[8][4] = {};
  bf16x8 af[4], bg[4];

  const int NT = K >> 5;  // 160 (gemm1) / 48 (gemm2); NT % 4 == 0

  // prologue: stage kslices 0,1,2 (12 loads); wait oldest 4 (t0 ready)
  STAGE_A(0, 0); STAGE_B(0, 0);
  STAGE_A(1, 1); STAGE_B(1, 1);
  STAGE_A(2, 2); STAGE_B(2, 2);
  VMBAR(8);

  for (int t = 0; t < NT - 4; t += 4) {
    KSTEP(0, STAGE_A(t + 3, 3), STAGE_B(t + 3, 3), VMBAR(8));
    KSTEP(1, STAGE_A(t + 4, 0), STAGE_B(t + 4, 0), VMBAR(8));
    KSTEP(2, STAGE_A(t + 5, 1), STAGE_B(t + 5, 1), VMBAR(8));
    KSTEP(3, STAGE_A(t + 6, 2), STAGE_B(t + 6, 2), VMBAR(8));
  }
  // tail: t = NT-4 .. NT-1
  KSTEP(0, STAGE_A(NT - 1, 3), STAGE_B(NT - 1, 3), VMBAR(8));
  KSTEP(1, (void)0, (void)0, VMBAR(4));
  KSTEP(2, (void)0, (void)0, VMBAR(0));
  KSTEP(3, (void)0, (void)0, (void)0);

  // C/D layout (m89-verified): col = lane&15, row = (lane>>4)*4 + reg.
  const int colb = n0 + (wcol << 6) + lr;
  const int rowb = m0 + (wrow << 7) + ((lane >> 4) << 2);
#pragma unroll
  for (int i = 0; i < 8; ++i)
#pragma unroll
    for (int j = 0; j < 4; ++j)
#pragma unroll
      for (int r = 0; r < 4; ++r) {
        if constexpr (FUSE_SILU) {
          // lanes (2k,2k+1) hold cols (gate_f, up_f) of the same row.
          float v = acc[i][j][r];
          float p = __shfl_xor(v, 1, 64);
          float g = (lane & 1) ? p : v;
          float u = (lane & 1) ? v : p;
          float hv = (g / (1.0f + __expf(-g))) * u;
          if ((lane & 1) == 0)
            C[(size_t)(rowb + i * 16 + r) * ldc + ((colb + j * 16) >> 1)] =
                (OutT)hv;
        } else {
          C[(size_t)(rowb + i * 16 + r) * ldc + (colb + j * 16)] =
              (OutT)acc[i][j][r];
        }
      }
}

extern "C" void kernel_launch(void* const* d_in, const int* in_sizes, int n_in,
                              void* d_out, int out_size, void* d_ws,
                              size_t ws_size, hipStream_t stream) {
  const int Hd = 5120, Fd = 1536, Td = 8192;
  const float* x = (const float*)d_in[0];
  const float* wg = (const float*)d_in[1];
  const float* sg = (const float*)d_in[2];
  const float* wu = (const float*)d_in[3];
  const float* su = (const float*)d_in[4];
  const float* wd = (const float*)d_in[5];
  const float* sd = (const float*)d_in[6];
  float* out = (float*)d_out;

  // ws layout (bf16): xb [T*H] | wq [2F*H] | wdq [H*F] | h [T*F]  ~156 MB
  __bf16* ws = (__bf16*)d_ws;
  const size_t xsz = (size_t)Td * Hd;
  __bf16* xb = ws;
  __bf16* wq = xb + xsz;
  __bf16* wdq = wq + (size_t)2 * Fd * Hd;
  __bf16* hbuf = wdq + (size_t)Hd * Fd;

  prep<<<32000, 256, 0, stream>>>(x, wg, sg, wu, su, wd, sd, xb, wq, wdq);

  // gemm1: [8192 x 3072] = xb @ wq^T, silu-pair epilogue -> h [8192][1536]
  // grid = (8192/256) * (3072/256) = 32 * 12 = 384  (%8==0)
  gemm_p<true, __bf16><<<384, 512, 0, stream>>>(xb, wq, hbuf, Td, 2 * Fd, Hd,
                                                Fd, 12);

  // gemm2: [8192 x 5120] = h @ wdq^T -> out f32
  // grid = 32 * 20 = 640  (%8==0)
  gemm_p<false, float><<<640, 512, 0, stream>>>(hbuf, wdq, out, Td, Hd, Fd,
                                                Hd, 20);
}

// Round 4
// 732.050 us; speedup vs baseline: 1.0234x; 1.0234x over previous
//
#include <hip/hip_runtime.h>

// DeepSeek-V2 expert MLP, fp8-block-dequant weights. T=8192, H=5120, F=1536.
// Pipeline (3 dispatches):
//   1) prep: x f32->bf16; wg,wu dequant->bf16 INTERLEAVED into wq[3072][5120];
//      wd dequant->bf16 wdq[5120][1536].  (unchanged, verified)
//   2) gemm_p<FUSE_SILU>: h = silu/up-pair epilogue of xb @ wq^T.
//   3) gemm_p<plain>: out = h @ wdq^T, f32.
// GEMM round-4: tile 128x256, 256 thr = 4 waves (1M x 4N, per-wave 128x64,
// acc[8][4] -- round-3's MFMA:ds_read ratio) in ring-3 LDS (3 x {A 8KB |
// B 16KB} = 72 KB) => 2 blocks/CU (round-2's co-residency mechanism: the
// other block covers barrier/vmcnt stalls; s_barrier syncs only 4 waves).
// Per kslice (BK=32): 2 phases x {ds_read | stage-issue | bar | lgkm0 |
// setprio 16 MFMA | bar}; 6 glds16/thread/kslice, counted VMBAR(6)
// (2 kslices in flight, never drained to 0 in the loop) [T3/T4].
// Kept verified: XOR swizzle (0 conflicts), linear glds dest +
// inverse-swizzled global src (rule #21), setprio [T5], bijective XCD
// chunk swizzle [T1] (grids 768 / 1280, both %8==0).

typedef __bf16 bf16x8 __attribute__((ext_vector_type(8)));
typedef float  f32x4  __attribute__((ext_vector_type(4)));

__device__ __forceinline__ void glds16(const __bf16* g, __bf16* l) {
  __builtin_amdgcn_global_load_lds(
      (const __attribute__((address_space(1))) void*)g,
      (__attribute__((address_space(3))) void*)l, 16, 0, 0);
}

// Inverse of the read-side swizzle: for linear 16B LDS chunk c of a region,
// which logical (row, k) must be fetched there. Subtile = 16 rows x
// 32 bf16 = 1024 B; storage byte = logical ^ ((row&8)<<2) ^ ((row&2)<<3).
__device__ __forceinline__ void chunk_rk(int c, int& row, int& k) {
  int s = c >> 6;                 // subtile index (16 rows each)
  int w = (c & 63) << 4;          // storage byte within subtile
  int wl = w ^ (((w >> 9) & 1) << 5) ^ (((w >> 7) & 1) << 4);
  row = (s << 4) + (wl >> 6);
  k = (wl & 63) >> 1;
}

#define BAR()                               \
  do {                                      \
    __builtin_amdgcn_sched_barrier(0);      \
    asm volatile("s_barrier" ::: "memory"); \
    __builtin_amdgcn_sched_barrier(0);      \
  } while (0)

#define LGKM0()                                        \
  do {                                                 \
    asm volatile("s_waitcnt lgkmcnt(0)" ::: "memory"); \
    __builtin_amdgcn_sched_barrier(0);                 \
  } while (0)

#define VMBAR(n)                                                       \
  do {                                                                 \
    __builtin_amdgcn_sched_barrier(0);                                 \
    asm volatile("s_waitcnt vmcnt(" #n ")\n\ts_barrier" ::: "memory"); \
    __builtin_amdgcn_sched_barrier(0);                                 \
  } while (0)

// ---- fused prep: xcast + 3 dequants in one launch (unchanged) -------------
__device__ __forceinline__ void cast8(const float* __restrict__ in,
                                      __bf16* __restrict__ out, size_t idx) {
  f32x4 a = *(const f32x4*)(in + idx);
  f32x4 b = *(const f32x4*)(in + idx + 4);
  bf16x8 o;
#pragma unroll
  for (int i = 0; i < 4; ++i) { o[i] = (__bf16)a[i]; o[i + 4] = (__bf16)b[i]; }
  *(bf16x8*)(out + idx) = o;
}

__device__ __forceinline__ void dq_ilv(const float* __restrict__ w,
                                       const float* __restrict__ s,
                                       __bf16* __restrict__ wq, int r, int tid,
                                       int which) {
  unsigned idx = ((unsigned)r * 256u + (unsigned)tid) * 8u;
  unsigned f = idx / 5120u;
  unsigned h = idx - f * 5120u;
  float sc = s[(f >> 7) * 40 + (h >> 7)];
  f32x4 a = *(const f32x4*)(w + idx);
  f32x4 b = *(const f32x4*)(w + idx + 4);
  bf16x8 o;
#pragma unroll
  for (int i = 0; i < 4; ++i) {
    o[i] = (__bf16)(a[i] * sc);
    o[i + 4] = (__bf16)(b[i] * sc);
  }
  *(bf16x8*)(wq + (size_t)(2 * f + which) * 5120 + h) = o;
}

__device__ __forceinline__ void dq_wd(const float* __restrict__ w,
                                      const float* __restrict__ s,
                                      __bf16* __restrict__ o8, int r, int tid) {
  unsigned idx = ((unsigned)r * 256u + (unsigned)tid) * 8u;
  unsigned f = idx / 1536u;
  unsigned h = idx - f * 1536u;
  float sc = s[(f >> 7) * 12 + (h >> 7)];
  f32x4 a = *(const f32x4*)(w + idx);
  f32x4 b = *(const f32x4*)(w + idx + 4);
  bf16x8 o;
#pragma unroll
  for (int i = 0; i < 4; ++i) {
    o[i] = (__bf16)(a[i] * sc);
    o[i + 4] = (__bf16)(b[i] * sc);
  }
  *(bf16x8*)(o8 + idx) = o;
}

__global__ void prep(const float* __restrict__ x, const float* __restrict__ wg,
                     const float* __restrict__ sg, const float* __restrict__ wu,
                     const float* __restrict__ su, const float* __restrict__ wd,
                     const float* __restrict__ sd, __bf16* __restrict__ xb,
                     __bf16* __restrict__ wq, __bf16* __restrict__ wdq) {
  int bid = blockIdx.x;
  int tid = threadIdx.x;
  if (bid < 20480) {
    cast8(x, xb, ((size_t)bid * 256 + tid) * 8);
  } else if (bid < 24320) {
    dq_ilv(wg, sg, wq, bid - 20480, tid, 0);
  } else if (bid < 28160) {
    dq_ilv(wu, su, wq, bid - 24320, tid, 1);
  } else {
    dq_wd(wd, sd, wdq, bid - 28160, tid);
  }
}

// ---- pipelined GEMM: C = A @ B^T ------------------------------------------
// A:[M,K] bf16, B:[N,K] bf16. Tile 128(M) x 256(N), 4 waves, kslice ring-3.
template <bool FUSE_SILU, typename OutT>
__global__ __launch_bounds__(256, 2) void gemm_p(
    const __bf16* __restrict__ A, const __bf16* __restrict__ B,
    OutT* __restrict__ C, int M, int N, int K, int ldc, int nbx) {
  __shared__ __bf16 lds[3 * 12288];  // slot = A 4096 + B 8192 bf16 = 24 KB
  const int tid = threadIdx.x;
  const int lane = tid & 63;
  const int wave = tid >> 6;   // 0..3 = N-wave (each wave: 128 x 64 output)
  const int lr = lane & 15;

  // bijective XCD-chunked swizzle (gridDim.x % 8 == 0 by construction)
  const int nwg = gridDim.x;
  const int lb = (blockIdx.x & 7) * (nwg >> 3) + (blockIdx.x >> 3);
  const int bx = lb % nbx;
  const int by = lb / nbx;
  const int m0 = by * 128, n0 = bx * 256;

  // per-lane fragment byte offset within a 1 KB subtile, swizzled
  int laneoff = (lr << 6) | ((lane >> 4) << 4);
  laneoff ^= ((lr & 2) << 3) | ((lr & 8) << 2);
  const int b_sub = wave << 2;   // wave's 4 B-subtiles (64 cols)

  // staging: per kslice each thread: A chunks {tid, tid+256} (8 KB total),
  // B chunks {tid, tid+256, tid+512, tid+768} (16 KB total); inverse-swizzled
  // global source, linear LDS destination.
  int rr[4], kk[4];
  chunk_rk(tid, rr[0], kk[0]);
  chunk_rk(tid + 256, rr[1], kk[1]);
  chunk_rk(tid + 512, rr[2], kk[2]);
  chunk_rk(tid + 768, rr[3], kk[3]);
  const unsigned o0 = (unsigned)rr[0] * K + (unsigned)kk[0];
  const unsigned o1 = (unsigned)rr[1] * K + (unsigned)kk[1];
  const unsigned o2 = (unsigned)rr[2] * K + (unsigned)kk[2];
  const unsigned o3 = (unsigned)rr[3] * K + (unsigned)kk[3];
  const int d0 = tid << 3, d1 = (tid + 256) << 3;
  const int d2 = (tid + 512) << 3, d3 = (tid + 768) << 3;
  const __bf16* Ab = A + (size_t)m0 * K;
  const __bf16* Bb = B + (size_t)n0 * K;

  f32x4 acc[8][4] = {};
  bf16x8 af[4], bg[4];

  auto STAGE_P0 = [&](int t, int s) {  // A (2 loads) + B lower half (2)
    __bf16* sb = lds + s * 12288;
    const unsigned ko = (unsigned)t << 5;
    glds16(Ab + (o0 + ko), sb + d0);
    glds16(Ab + (o1 + ko), sb + d1);
    glds16(Bb + (o0 + ko), sb + 4096 + d0);
    glds16(Bb + (o1 + ko), sb + 4096 + d1);
  };
  auto STAGE_P1 = [&](int t, int s) {  // B upper half (2 loads)
    __bf16* sb = lds + s * 12288;
    const unsigned ko = (unsigned)t << 5;
    glds16(Bb + (o2 + ko), sb + 4096 + d2);
    glds16(Bb + (o3 + ko), sb + 4096 + d3);
  };
  auto RD_AF = [&](const char* base, int h) {
#pragma unroll
    for (int i = 0; i < 4; ++i)
      af[i] = *(const bf16x8*)(base + (((h << 2) + i) << 10) + laneoff);
  };
  auto RD_BG = [&](const char* base) {
#pragma unroll
    for (int j = 0; j < 4; ++j)
      bg[j] = *(const bf16x8*)(base + 8192 + ((b_sub + j) << 10) + laneoff);
  };
  auto MFMA16 = [&](int h) {
    __builtin_amdgcn_s_setprio(1);
#pragma unroll
    for (int j = 0; j < 4; ++j)
#pragma unroll
      for (int i = 0; i < 4; ++i)
        acc[(h << 2) + i][j] = __builtin_amdgcn_mfma_f32_16x16x32_bf16(
            af[i], bg[j], acc[(h << 2) + i][j], 0, 0, 0);
    __builtin_amdgcn_s_setprio(0);
  };

  const int NT = K >> 5;  // 160 (gemm1) / 48 (gemm2)

  // prologue: stage kslices 0,1 (12 loads); wait oldest 6 (slice 0 ready)
  STAGE_P0(0, 0);
  STAGE_P1(0, 0);
  STAGE_P0(1, 1);
  STAGE_P1(1, 1);
  VMBAR(6);

  int cur = 0, stg = 2;
  for (int t = 0; t < NT - 2; ++t) {
    const char* cb = (const char*)lds + cur * 24576;
    RD_AF(cb, 0);
    RD_BG(cb);
    STAGE_P0(t + 2, stg);
    BAR();
    LGKM0();
    MFMA16(0);
    BAR();
    RD_AF(cb, 1);
    STAGE_P1(t + 2, stg);
    BAR();
    LGKM0();
    MFMA16(1);
    VMBAR(6);  // slice t+1 fully staged; slice t+2's 6 loads stay in flight
    cur = (cur == 2) ? 0 : cur + 1;
    stg = (stg == 2) ? 0 : stg + 1;
  }
  {  // t = NT-2: no staging; drain to 0 so slice NT-1 is readable
    const char* cb = (const char*)lds + cur * 24576;
    RD_AF(cb, 0);
    RD_BG(cb);
    BAR();
    LGKM0();
    MFMA16(0);
    BAR();
    RD_AF(cb, 1);
    BAR();
    LGKM0();
    MFMA16(1);
    VMBAR(0);
    cur = (cur == 2) ? 0 : cur + 1;
  }
  {  // t = NT-1: last slice
    const char* cb = (const char*)lds + cur * 24576;
    RD_AF(cb, 0);
    RD_BG(cb);
    LGKM0();
    MFMA16(0);
    RD_AF(cb, 1);
    LGKM0();
    MFMA16(1);
  }

  // C/D layout (m89-verified): col = lane&15, row = (lane>>4)*4 + reg.
  const int colb = n0 + (wave << 6) + lr;
  const int rowb = m0 + ((lane >> 4) << 2);
#pragma unroll
  for (int i = 0; i < 8; ++i)
#pragma unroll
    for (int j = 0; j < 4; ++j)
#pragma unroll
      for (int r = 0; r < 4; ++r) {
        if constexpr (FUSE_SILU) {
          // lanes (2k,2k+1) hold cols (gate_f, up_f) of the same row.
          float v = acc[i][j][r];
          float p = __shfl_xor(v, 1, 64);
          float g = (lane & 1) ? p : v;
          float u = (lane & 1) ? v : p;
          float hv = (g / (1.0f + __expf(-g))) * u;
          if ((lane & 1) == 0)
            C[(size_t)(rowb + i * 16 + r) * ldc + ((colb + j * 16) >> 1)] =
                (OutT)hv;
        } else {
          C[(size_t)(rowb + i * 16 + r) * ldc + (colb + j * 16)] =
              (OutT)acc[i][j][r];
        }
      }
}

extern "C" void kernel_launch(void* const* d_in, const int* in_sizes, int n_in,
                              void* d_out, int out_size, void* d_ws,
                              size_t ws_size, hipStream_t stream) {
  const int Hd = 5120, Fd = 1536, Td = 8192;
  const float* x = (const float*)d_in[0];
  const float* wg = (const float*)d_in[1];
  const float* sg = (const float*)d_in[2];
  const float* wu = (const float*)d_in[3];
  const float* su = (const float*)d_in[4];
  const float* wd = (const float*)d_in[5];
  const float* sd = (const float*)d_in[6];
  float* out = (float*)d_out;

  // ws layout (bf16): xb [T*H] | wq [2F*H] | wdq [H*F] | h [T*F]  ~156 MB
  __bf16* ws = (__bf16*)d_ws;
  const size_t xsz = (size_t)Td * Hd;
  __bf16* xb = ws;
  __bf16* wq = xb + xsz;
  __bf16* wdq = wq + (size_t)2 * Fd * Hd;
  __bf16* hbuf = wdq + (size_t)Hd * Fd;

  prep<<<32000, 256, 0, stream>>>(x, wg, sg, wu, su, wd, sd, xb, wq, wdq);

  // gemm1: [8192 x 3072] = xb @ wq^T, silu-pair epilogue -> h [8192][1536]
  // grid = (8192/128) * (3072/256) = 64 * 12 = 768 (%8==0); 2 blk/CU
  gemm_p<true, __bf16><<<768, 256, 0, stream>>>(xb, wq, hbuf, Td, 2 * Fd, Hd,
                                                Fd, 12);

  // gemm2: [8192 x 5120] = h @ wdq^T -> out f32
  // grid = 64 * 20 = 1280 (%8==0); 2 blk/CU
  gemm_p<false, float><<<1280, 256, 0, stream>>>(hbuf, wdq, out, Td, Hd, Fd,
                                                 Hd, 20);
}